// Round 17
// baseline (784.640 us; speedup 1.0000x reference)
//
#include <hip/hip_runtime.h>
#include <hip/hip_bf16.h>
#include <hip/hip_cooperative_groups.h>

namespace cg = cooperative_groups;

// GCN encoder: h = relu(Agg(h @ W)) x3 (input linear folded into layer 0).
// N=20000 nodes, E=640000 edges, H=128.
// History: R2 CSR pull (3330->367) ... R7 MFMA bf16-split GEMM (245),
// R9/R10 bf16 payload + L2-sliced agg, de-LDS'd (197..193), R13 rank-trick
// CSR (169), R14 warm-up + W_in@Ws0 fold (160), R15 coop mega-kernel FAILED
// (unchecked launch error; grid > co-residency), R16 direct-x layer 0 (157.9).
// R17: mega-kernel RETRY with runtime occupancy query (grid =
//   min(maxActive*numCU, 2048)) + checked launch + R16-kernel fallback if
//   the cooperative path is unavailable. 9 grid.syncs replace 9 dispatch
//   boundaries (~45us of launch/drain). fill overlapped with mgemm L0.
// ws: [dis N f][off4 4N+4 i][csr E i][rank E i][hh N*128 bf16][hl N*128 bf16]
//     [xwb 2xNx64 bf16][bc 128 f][bsum 128 i]    Wf = d_out[0:192KB] scratch.

#define HDIM 128

typedef __attribute__((ext_vector_type(8))) short s8v;
typedef __attribute__((ext_vector_type(4))) float f4v;

__device__ __forceinline__ ushort f2bf(float f) {
    uint u = __float_as_uint(f);
    u += 0x7FFFu + ((u >> 16) & 1u);      // round-to-nearest-even
    return (ushort)(u >> 16);
}
__device__ __forceinline__ float bf2f(ushort h) {
    return __uint_as_float(((uint)h) << 16);
}
__device__ __forceinline__ void split8(float4 a, float4 b, s8v& hi, s8v& lo) {
    ushort h0 = f2bf(a.x), h1 = f2bf(a.y), h2 = f2bf(a.z), h3 = f2bf(a.w);
    ushort h4 = f2bf(b.x), h5 = f2bf(b.y), h6 = f2bf(b.z), h7 = f2bf(b.w);
    hi[0] = (short)h0; hi[1] = (short)h1; hi[2] = (short)h2; hi[3] = (short)h3;
    hi[4] = (short)h4; hi[5] = (short)h5; hi[6] = (short)h6; hi[7] = (short)h7;
    lo[0] = (short)f2bf(a.x - bf2f(h0)); lo[1] = (short)f2bf(a.y - bf2f(h1));
    lo[2] = (short)f2bf(a.z - bf2f(h2)); lo[3] = (short)f2bf(a.w - bf2f(h3));
    lo[4] = (short)f2bf(b.x - bf2f(h4)); lo[5] = (short)f2bf(b.y - bf2f(h5));
    lo[6] = (short)f2bf(b.z - bf2f(h6)); lo[7] = (short)f2bf(b.w - bf2f(h7));
}

// ======================= shared phase bodies (device) =======================

__device__ __forceinline__ void mgemm_body(
    int work, int gsz, int bid, int tid, bool l0,
    const float* xf, const ushort* Ahi, const ushort* Alo,
    const ushort* Wfm, const float* bias, const float* dis,
    ushort* xwb, int M) {
    int l = tid & 63;
    int lr = l & 15, lk = l >> 4;
    for (int vb = bid; vb < work; vb += gsz) {
        int ch = vb & 1;
        int strip = (vb >> 1) * 4 + (tid >> 6);
        int r0 = strip * 16;
        int ar = r0 + lr; if (ar >= M) ar = M - 1;

        s8v ah0, ah1, ah2, ah3, al0, al1, al2, al3;
        if (l0) {
            const float* xr = xf + (long long)ar * HDIM + lk * 8;
            split8(*(const float4*)(xr),      *(const float4*)(xr + 4),   ah0, al0);
            split8(*(const float4*)(xr + 32), *(const float4*)(xr + 36),  ah1, al1);
            split8(*(const float4*)(xr + 64), *(const float4*)(xr + 68),  ah2, al2);
            split8(*(const float4*)(xr + 96), *(const float4*)(xr + 100), ah3, al3);
        } else {
            ah0 = *(const s8v*)(Ahi + (long long)ar * HDIM + lk * 8);
            ah1 = *(const s8v*)(Ahi + (long long)ar * HDIM + lk * 8 + 32);
            ah2 = *(const s8v*)(Ahi + (long long)ar * HDIM + lk * 8 + 64);
            ah3 = *(const s8v*)(Ahi + (long long)ar * HDIM + lk * 8 + 96);
            al0 = *(const s8v*)(Alo + (long long)ar * HDIM + lk * 8);
            al1 = *(const s8v*)(Alo + (long long)ar * HDIM + lk * 8 + 32);
            al2 = *(const s8v*)(Alo + (long long)ar * HDIM + lk * 8 + 64);
            al3 = *(const s8v*)(Alo + (long long)ar * HDIM + lk * 8 + 96);
        }

        f4v acc[4];
        #pragma unroll
        for (int c = 0; c < 4; ++c) acc[c] = (f4v){0.f, 0.f, 0.f, 0.f};

#define KSTEP(AH, AL, ksi)                                                          \
    {                                                                               \
        const ushort* wb = Wfm + ((ksi) * 8 + ch * 4) * 512 + l * 8;                \
        _Pragma("unroll")                                                           \
        for (int c = 0; c < 4; ++c) {                                               \
            s8v bh = *(const s8v*)(wb + c * 512);                                   \
            s8v bl = *(const s8v*)(wb + 16384 + c * 512);                           \
            acc[c] = __builtin_amdgcn_mfma_f32_16x16x32_bf16(AH, bh, acc[c], 0,0,0);\
            acc[c] = __builtin_amdgcn_mfma_f32_16x16x32_bf16(AH, bl, acc[c], 0,0,0);\
            acc[c] = __builtin_amdgcn_mfma_f32_16x16x32_bf16(AL, bh, acc[c], 0,0,0);\
        }                                                                           \
    }
        KSTEP(ah0, al0, 0)
        KSTEP(ah1, al1, 1)
        KSTEP(ah2, al2, 2)
        KSTEP(ah3, al3, 3)
#undef KSTEP

        if (r0 < M) {
            float bbv[4], sc[4];
            #pragma unroll
            for (int c = 0; c < 4; ++c)
                bbv[c] = bias ? bias[(ch * 4 + c) * 16 + lr] : 0.f;
            #pragma unroll
            for (int j = 0; j < 4; ++j) {
                int rr = r0 + lk * 4 + j;
                sc[j] = (rr < M) ? dis[rr] : 0.f;
            }
            #pragma unroll
            for (int c = 0; c < 4; ++c) {
                #pragma unroll
                for (int j = 0; j < 4; ++j) {
                    int row = r0 + lk * 4 + j;
                    if (row < M) {
                        float o = (acc[c][j] + bbv[c]) * sc[j];
                        int cc = c * 16 + lr;
                        xwb[((long long)ch * M + row) * 64 + cc] = f2bf(o);
                    }
                }
            }
        }
    }
}

__device__ __forceinline__ void agg_body(
    int gsz, int bid, int tid, bool last,
    const int* off4, const int* csr, const float* dis,
    const ushort* xwb, const float* bvec,
    float* outf, ushort* outhi, ushort* outlo, int N) {
    int lane = tid & 63;
    int wv = tid >> 6;
    int t4 = lane & 15, q = lane >> 4;
    int sl = bid & 1;
    const ushort* xs = xwb + (long long)sl * N * 64;

    {   // L2 warm-up: stream slice linearly (asm-kept-alive)
        int lb = bid >> 3;
        int nlb = gsz >> 3; if (nlb < 1) nlb = 1;
        const float4* p4 = (const float4*)xs;
        int tot = N * 8;
        int chunk = (tot + nlb - 1) / nlb;
        int lo = lb * chunk;
        int hi = lo + chunk; if (hi > tot) hi = tot;
        float wacc = 0.f;
        for (int i = lo + tid; i < hi; i += 256) {
            float4 u = p4[i];
            wacc += (u.x + u.y) + (u.z + u.w);
        }
        asm volatile("" :: "v"(wacc));
    }

    float4 bb = ((const float4*)(bvec + sl * 64))[t4];
    int v0 = (bid >> 1) * 4 + wv;
    int vstride = (gsz >> 1) * 4;

#define GATH(sidx)                                                          \
    {                                                                       \
        uint2 u = *(const uint2*)(xs + (long long)(sidx) * 64 + (t4 << 2)); \
        ax += bf2f((ushort)u.x); ay += bf2f((ushort)(u.x >> 16));           \
        az += bf2f((ushort)u.y); aw += bf2f((ushort)(u.y >> 16));           \
    }
#define SEL(c) (q == 0 ? (c).x : q == 1 ? (c).y : q == 2 ? (c).z : (c).w)

    for (int v = v0; v < N; v += vstride) {
        int start = off4[v << 2];
        int end   = off4[(v << 2) + 4];
        float dv = dis[v];

        float ax = 0.f, ay = 0.f, az = 0.f, aw = 0.f;
        if (q == 0) GATH(v);

        int i = start;
        for (; i + 32 <= end; i += 32) {
            int ib = __builtin_amdgcn_readfirstlane(i);
            int4 c0 = *(const int4*)(csr + ib);
            int4 c1 = *(const int4*)(csr + ib + 4);
            int4 c2 = *(const int4*)(csr + ib + 8);
            int4 c3 = *(const int4*)(csr + ib + 12);
            int4 c4 = *(const int4*)(csr + ib + 16);
            int4 c5 = *(const int4*)(csr + ib + 20);
            int4 c6 = *(const int4*)(csr + ib + 24);
            int4 c7 = *(const int4*)(csr + ib + 28);
            int s0 = SEL(c0), s1 = SEL(c1), s2 = SEL(c2), s3 = SEL(c3);
            int s4 = SEL(c4), s5 = SEL(c5), s6 = SEL(c6), s7 = SEL(c7);
            GATH(s0); GATH(s1); GATH(s2); GATH(s3);
            GATH(s4); GATH(s5); GATH(s6); GATH(s7);
        }
        if (i + 16 <= end) {
            int ib = __builtin_amdgcn_readfirstlane(i);
            int4 c0 = *(const int4*)(csr + ib);
            int4 c1 = *(const int4*)(csr + ib + 4);
            int4 c2 = *(const int4*)(csr + ib + 8);
            int4 c3 = *(const int4*)(csr + ib + 12);
            int s0 = SEL(c0), s1 = SEL(c1), s2 = SEL(c2), s3 = SEL(c3);
            GATH(s0); GATH(s1); GATH(s2); GATH(s3);
            i += 16;
        }
        if (i + 8 <= end) {
            int ib = __builtin_amdgcn_readfirstlane(i);
            int4 c0 = *(const int4*)(csr + ib);
            int4 c1 = *(const int4*)(csr + ib + 4);
            int s0 = SEL(c0), s1 = SEL(c1);
            GATH(s0); GATH(s1);
            i += 8;
        }
        if (i + 4 <= end) {
            int ib = __builtin_amdgcn_readfirstlane(i);
            int4 c0 = *(const int4*)(csr + ib);
            int s0 = SEL(c0);
            GATH(s0);
            i += 4;
        }
        {
            int r = end - i;
            if (q < r) {
                int s = csr[__builtin_amdgcn_readfirstlane(i) + q];
                GATH(s);
            }
        }

        ax += __shfl_xor(ax, 16); ax += __shfl_xor(ax, 32);
        ay += __shfl_xor(ay, 16); ay += __shfl_xor(ay, 32);
        az += __shfl_xor(az, 16); az += __shfl_xor(az, 32);
        aw += __shfl_xor(aw, 16); aw += __shfl_xor(aw, 32);

        if (q == 0) {
            float ox = fmaxf(fmaf(dv, ax, bb.x), 0.f);
            float oy = fmaxf(fmaf(dv, ay, bb.y), 0.f);
            float oz = fmaxf(fmaf(dv, az, bb.z), 0.f);
            float ow = fmaxf(fmaf(dv, aw, bb.w), 0.f);
            long long oidx = (long long)v * HDIM + sl * 64 + (t4 << 2);
            if (last) {
                *(float4*)(outf + oidx) = make_float4(ox, oy, oz, ow);
            } else {
                ushort h0 = f2bf(ox), h1 = f2bf(oy), h2 = f2bf(oz), h3 = f2bf(ow);
                uint2 ph, pl;
                ph.x = (uint)h0 | ((uint)h1 << 16);
                ph.y = (uint)h2 | ((uint)h3 << 16);
                pl.x = (uint)f2bf(ox - bf2f(h0)) | ((uint)f2bf(oy - bf2f(h1)) << 16);
                pl.y = (uint)f2bf(oz - bf2f(h2)) | ((uint)f2bf(ow - bf2f(h3)) << 16);
                *(uint2*)(outhi + oidx) = ph;
                *(uint2*)(outlo + oidx) = pl;
            }
        }
    }
#undef GATH
#undef SEL
}

// ======================= cooperative mega-kernel ============================

__global__ __launch_bounds__(256, 4) void k_gcn(
    const float* __restrict__ x, const int* __restrict__ src,
    const int* __restrict__ dst, const float* __restrict__ W_in,
    const float* __restrict__ b_in, const float* __restrict__ Ws,
    const float* __restrict__ bs,
    float* __restrict__ dis, int* __restrict__ off4,
    int* __restrict__ csr, int* __restrict__ rank,
    ushort* __restrict__ hh, ushort* __restrict__ hl,
    ushort* __restrict__ xwb, float* __restrict__ bc,
    int* __restrict__ bsum,
    ushort* Wf, float* outf,            // both alias d_out -- no restrict
    int N, int E) {

    cg::grid_group grid = cg::this_grid();
    const int bid = blockIdx.x;
    const int tid = threadIdx.x;
    const int gsz = gridDim.x;
    const int gthreads = gsz * 256;
    const int gtid = bid * 256 + tid;

    // ---- S0: zero off4 | wconv (m=0 folds W_in@Ws0) | bc ----
    for (int i = gtid; i < 4 * N + 4; i += gthreads) off4[i] = 0;

    for (int idx = gtid; idx < 3 * 16384; idx += gthreads) {
        int m = idx >> 14;
        int e = idx & 16383;
        int k = e >> 7, col = e & 127;
        float w;
        if (m == 0) {
            w = 0.f;
            #pragma unroll 8
            for (int j = 0; j < 128; ++j)
                w = fmaf(W_in[k * 128 + j], Ws[j * 128 + col], w);
        } else {
            w = Ws[m * 16384 + k * 128 + col];
        }
        ushort hi = f2bf(w);
        ushort lo = f2bf(w - bf2f(hi));
        int ks = k >> 5, lk = (k >> 3) & 3, j = k & 7;
        int ct = col >> 4, lane = lk * 16 + (col & 15);
        int o = m * 32768 + (ks * 8 + ct) * 512 + lane * 8 + j;
        Wf[o] = hi;
        Wf[o + 16384] = lo;
    }

    if (bid == 0 && tid < 128) {
        float v = 0.f;
        #pragma unroll 8
        for (int j = 0; j < 128; ++j)
            v = fmaf(b_in[j], Ws[j * 128 + tid], v);
        bc[tid] = v;
    }
    grid.sync();

    // ---- S1: count + rank ----
    for (int t = gtid; t < E / 4; t += gthreads) {
        int4 d = ((const int4*)dst)[t];
        int4 r;
        r.x = atomicAdd(&off4[d.x * 4 + 0], 1);
        r.y = atomicAdd(&off4[d.y * 4 + 1], 1);
        r.z = atomicAdd(&off4[d.z * 4 + 2], 1);
        r.w = atomicAdd(&off4[d.w * 4 + 3], 1);
        ((int4*)rank)[t] = r;
    }
    grid.sync();

    // ---- S2: tile-local scan + dis ----
    const int total = N * 4;
    const int ntiles = (total + 1023) >> 10;
    if (bid < ntiles) {
        int base = bid * 1024 + tid * 4;
        int4 d = make_int4(0, 0, 0, 0);
        if (base < total) {
            d = *(const int4*)(off4 + base);
            dis[base >> 2] = rsqrtf((float)(d.x + d.y + d.z + d.w + 1));
        }
        int tsum = d.x + d.y + d.z + d.w;
        int lane = tid & 63;
        int incl = tsum;
        #pragma unroll
        for (int ofs = 1; ofs < 64; ofs <<= 1) {
            int u = __shfl_up(incl, ofs);
            if (lane >= ofs) incl += u;
        }
        __shared__ int wsum[4];
        if (lane == 63) wsum[tid >> 6] = incl;
        __syncthreads();
        int w = tid >> 6;
        int woff = 0;
        for (int i = 0; i < w; ++i) woff += wsum[i];
        int run = woff + incl - tsum;
        if (base < total) {
            off4[base + 0] = run; run += d.x;
            off4[base + 1] = run; run += d.y;
            off4[base + 2] = run; run += d.z;
            off4[base + 3] = run;
        }
        if (tid == 255) bsum[bid] = woff + incl;
    }
    grid.sync();

    // ---- S3: add tile-prefix + sentinel ----
    if (bid == 0 && tid == 0) off4[N * 4] = E;
    if (bid > 0 && bid < ntiles) {
        int p = 0;
        for (int i = 0; i < bid; ++i) p += bsum[i];
        int base = bid * 1024 + tid * 4;
        if (base < total) {
            int4 v = *(const int4*)(off4 + base);
            v.x += p; v.y += p; v.z += p; v.w += p;
            *(int4*)(off4 + base) = v;
        }
    }
    grid.sync();

    // ---- S4: fill (atomic-free) + mgemm L0 (direct-x) ----
    for (int t = gtid; t < E / 4; t += gthreads) {
        int4 s = ((const int4*)src)[t];
        int4 d = ((const int4*)dst)[t];
        int4 r = ((const int4*)rank)[t];
        csr[off4[d.x * 4 + 0] + r.x] = s.x;
        csr[off4[d.y * 4 + 1] + r.y] = s.y;
        csr[off4[d.z * 4 + 2] + r.z] = s.z;
        csr[off4[d.w * 4 + 3] + r.w] = s.w;
    }
    const int strips = (N + 15) >> 4;
    const int nbmg = 2 * ((strips + 3) >> 2);
    mgemm_body(nbmg, gsz, bid, tid, true, x, nullptr, nullptr,
               Wf, bc, dis, xwb, N);
    grid.sync();

    // ---- S5..S9: agg L0, mgemm L1, agg L1, mgemm L2, agg L2 ----
    agg_body(gsz, bid, tid, false, off4, csr, dis, xwb, bs + 0 * HDIM,
             nullptr, hh, hl, N);
    grid.sync();
    mgemm_body(nbmg, gsz, bid, tid, false, nullptr, hh, hl,
               Wf + 32768, nullptr, dis, xwb, N);
    grid.sync();
    agg_body(gsz, bid, tid, false, off4, csr, dis, xwb, bs + 1 * HDIM,
             nullptr, hh, hl, N);
    grid.sync();
    mgemm_body(nbmg, gsz, bid, tid, false, nullptr, hh, hl,
               Wf + 65536, nullptr, dis, xwb, N);
    grid.sync();
    agg_body(gsz, bid, tid, true, off4, csr, dis, xwb, bs + 2 * HDIM,
             outf, nullptr, nullptr, N);
}

// ======================= fallback kernels (R16) =============================

__global__ __launch_bounds__(256) void k_count(const int* __restrict__ dst,
                                               int* __restrict__ off4,
                                               int* __restrict__ rank, int E4) {
    int t = blockIdx.x * 256 + threadIdx.x;
    if (t >= E4) return;
    int4 d = ((const int4*)dst)[t];
    int4 r;
    r.x = atomicAdd(&off4[d.x * 4 + 0], 1);
    r.y = atomicAdd(&off4[d.y * 4 + 1], 1);
    r.z = atomicAdd(&off4[d.z * 4 + 2], 1);
    r.w = atomicAdd(&off4[d.w * 4 + 3], 1);
    ((int4*)rank)[t] = r;
}

__global__ __launch_bounds__(256) void k_scan_blk(int* __restrict__ off4,
                                                  float* __restrict__ dis,
                                                  int* __restrict__ bsum, int N) {
    int t = threadIdx.x;
    int total = N * 4;
    int base = blockIdx.x * 1024 + t * 4;
    int4 d = make_int4(0, 0, 0, 0);
    if (base < total) {
        d = *(const int4*)(off4 + base);
        dis[base >> 2] = rsqrtf((float)(d.x + d.y + d.z + d.w + 1));
    }
    int tsum = d.x + d.y + d.z + d.w;
    int lane = t & 63;
    int incl = tsum;
    #pragma unroll
    for (int ofs = 1; ofs < 64; ofs <<= 1) {
        int u = __shfl_up(incl, ofs);
        if (lane >= ofs) incl += u;
    }
    __shared__ int wsum[4];
    if (lane == 63) wsum[t >> 6] = incl;
    __syncthreads();
    int w = t >> 6;
    int woff = 0;
    for (int i = 0; i < w; ++i) woff += wsum[i];
    int run = woff + incl - tsum;
    if (base < total) {
        off4[base + 0] = run; run += d.x;
        off4[base + 1] = run; run += d.y;
        off4[base + 2] = run; run += d.z;
        off4[base + 3] = run;
    }
    if (t == 255) bsum[blockIdx.x] = woff + incl;
}

__global__ __launch_bounds__(256) void k_scan_add(int* __restrict__ off4,
                                                  const int* __restrict__ bsum,
                                                  int N, int E) {
    int bid = blockIdx.x;
    if (bid == 0) {
        if (threadIdx.x == 0) off4[N * 4] = E;
        return;
    }
    int p = 0;
    for (int i = 0; i < bid; ++i) p += bsum[i];
    int base = bid * 1024 + threadIdx.x * 4;
    if (base < N * 4) {
        int4 v = *(const int4*)(off4 + base);
        v.x += p; v.y += p; v.z += p; v.w += p;
        *(int4*)(off4 + base) = v;
    }
}

__global__ __launch_bounds__(256) void k_fill(const int* __restrict__ src,
                                              const int* __restrict__ dst,
                                              const int* __restrict__ off4,
                                              const int* __restrict__ rank,
                                              int* __restrict__ csr, int E4) {
    int t = blockIdx.x * 256 + threadIdx.x;
    if (t >= E4) return;
    int4 s = ((const int4*)src)[t];
    int4 d = ((const int4*)dst)[t];
    int4 r = ((const int4*)rank)[t];
    csr[off4[d.x * 4 + 0] + r.x] = s.x;
    csr[off4[d.y * 4 + 1] + r.y] = s.y;
    csr[off4[d.z * 4 + 2] + r.z] = s.z;
    csr[off4[d.w * 4 + 3] + r.w] = s.w;
}

__global__ __launch_bounds__(256) void k_pre(const float* __restrict__ W_in,
                                             const float* __restrict__ Ws,
                                             const float* __restrict__ b_in,
                                             ushort* __restrict__ Wf,
                                             float* __restrict__ bc,
                                             int* __restrict__ off4,
                                             int N, int nbZ) {
    int bid = blockIdx.x;
    if (bid < nbZ) {
        int i = bid * 256 + threadIdx.x;
        if (i < N * 4 + 4) off4[i] = 0;
    } else if (bid < nbZ + 192) {
        int idx = (bid - nbZ) * 256 + threadIdx.x;
        int m = idx >> 14;
        int e = idx & 16383;
        int k = e >> 7, col = e & 127;
        float w;
        if (m == 0) {
            w = 0.f;
            #pragma unroll 8
            for (int j = 0; j < 128; ++j)
                w = fmaf(W_in[k * 128 + j], Ws[j * 128 + col], w);
        } else {
            w = Ws[m * 16384 + k * 128 + col];
        }
        ushort hi = f2bf(w);
        ushort lo = f2bf(w - bf2f(hi));
        int ks = k >> 5, lk = (k >> 3) & 3, j = k & 7;
        int ct = col >> 4, lane = lk * 16 + (col & 15);
        int o = m * 32768 + (ks * 8 + ct) * 512 + lane * 8 + j;
        Wf[o] = hi;
        Wf[o + 16384] = lo;
    } else {
        int col = threadIdx.x;
        if (col < 128) {
            float v = 0.f;
            #pragma unroll 8
            for (int j = 0; j < 128; ++j)
                v = fmaf(b_in[j], Ws[j * 128 + col], v);
            bc[col] = v;
        }
    }
}

template<int L0>
__global__ __launch_bounds__(256) void k_mgemm(const ushort* Ahi, const ushort* Alo,
                                               const float* __restrict__ xf,
                                               const ushort* __restrict__ Wf,
                                               const float* __restrict__ bias,
                                               const float* __restrict__ scale,
                                               ushort* xwb, int M) {
    mgemm_body(gridDim.x, gridDim.x, blockIdx.x, threadIdx.x, L0 != 0,
               xf, Ahi, Alo, Wf, bias, scale, xwb, M);
}

template<int LAST>
__global__ __launch_bounds__(256) void k_agg(const int* __restrict__ off4,
                                             const int* __restrict__ csr,
                                             const float* __restrict__ dis,
                                             const ushort* __restrict__ xwb,
                                             const float* __restrict__ b,
                                             float* __restrict__ outf,
                                             ushort* __restrict__ outhi,
                                             ushort* __restrict__ outlo, int N) {
    agg_body(gridDim.x, blockIdx.x, threadIdx.x, LAST != 0,
             off4, csr, dis, xwb, b, outf, outhi, outlo, N);
}

// ======================= launcher ===========================================

extern "C" void kernel_launch(void* const* d_in, const int* in_sizes, int n_in,
                              void* d_out, int out_size, void* d_ws, size_t ws_size,
                              hipStream_t stream) {
    const float* x    = (const float*)d_in[0];
    const int*   ei   = (const int*)d_in[1];
    const float* W_in = (const float*)d_in[2];
    const float* b_in = (const float*)d_in[3];
    const float* Ws   = (const float*)d_in[4];
    const float* bs   = (const float*)d_in[5];

    const int N = in_sizes[0] / HDIM;
    const int E = in_sizes[1] / 2;
    const int* src = ei;
    const int* dst = ei + E;

    float*  dis  = (float*)d_ws;
    int*    off4 = (int*)(dis + N);
    int*    csr  = off4 + 4 * N + 4;
    int*    rank = csr + E;
    ushort* hh   = (ushort*)(rank + E);
    ushort* hl   = hh + (long long)N * HDIM;
    ushort* xwb  = hl + (long long)N * HDIM;
    float*  bc   = (float*)(xwb + (long long)2 * N * 64);
    int*    bsum = (int*)(bc + 128);
    ushort* Wf   = (ushort*)d_out;
    float*  outf = (float*)d_out;

    // ---- try cooperative mega-kernel, sized by runtime occupancy ----
    int ma = 0;
    hipError_t qe = hipOccupancyMaxActiveBlocksPerMultiprocessor(
        &ma, (const void*)k_gcn, 256, 0);
    int numCU = 256;
    hipDevice_t dev0;
    if (hipGetDevice(&dev0) == hipSuccess) {
        int c = 0;
        if (hipDeviceGetAttribute(&c, hipDeviceAttributeMultiprocessorCount,
                                  dev0) == hipSuccess && c > 0)
            numCU = c;
    }
    bool coop_done = false;
    if (qe == hipSuccess && ma > 0) {
        long long g = (long long)ma * numCU;
        if (g > 2048) g = 2048;
        int grid = (int)(g & ~7LL);
        int ntiles = (4 * N + 1023) / 1024;
        if (grid >= ntiles + 8 && grid >= 88) {
            int N_ = N, E_ = E;
            const float* x_ = x; const int* src_ = src; const int* dst_ = dst;
            const float* Win_ = W_in; const float* bin_ = b_in;
            const float* Ws_ = Ws; const float* bs_ = bs;
            float* dis_ = dis; int* off4_ = off4; int* csr_ = csr;
            int* rank_ = rank; ushort* hh_ = hh; ushort* hl_ = hl;
            ushort* xwb_ = xwb; float* bc_ = bc; int* bsum_ = bsum;
            ushort* Wf_ = Wf; float* outf_ = outf;
            void* args[] = {
                (void*)&x_, (void*)&src_, (void*)&dst_, (void*)&Win_,
                (void*)&bin_, (void*)&Ws_, (void*)&bs_, (void*)&dis_,
                (void*)&off4_, (void*)&csr_, (void*)&rank_, (void*)&hh_,
                (void*)&hl_, (void*)&xwb_, (void*)&bc_, (void*)&bsum_,
                (void*)&Wf_, (void*)&outf_, (void*)&N_, (void*)&E_
            };
            if (hipLaunchCooperativeKernel((void*)k_gcn, dim3(grid), dim3(256),
                                           args, 0, stream) == hipSuccess)
                coop_done = true;
        }
    }
    if (coop_done) return;

    // ---- fallback: proven R16 multi-kernel pipeline ----
    int nbZ     = (4 * N + 4 + 255) / 256;
    int nb_E4   = (E / 4 + 255) / 256;
    int nb_scan = (4 * N + 1023) / 1024;
    int strips  = (N + 15) / 16;
    int nb_mg   = 2 * ((strips + 3) / 4);
    int nb_pre  = nbZ + 192 + 1;
    int nb_agg  = 2048;

    k_pre<<<nb_pre, 256, 0, stream>>>(W_in, Ws, b_in, Wf, bc, off4, N, nbZ);
    k_count   <<<nb_E4,   256, 0, stream>>>(dst, off4, rank, E / 4);
    k_scan_blk<<<nb_scan, 256, 0, stream>>>(off4, dis, csr, N);
    k_scan_add<<<nb_scan, 256, 0, stream>>>(off4, csr, N, E);
    k_fill    <<<nb_E4,   256, 0, stream>>>(src, dst, off4, rank, csr, E / 4);

    for (int layer = 0; layer < 3; ++layer) {
        const ushort* Wfm = Wf + (long long)layer * 32768;
        const float* b = bs + (long long)layer * HDIM;
        if (layer == 0)
            k_mgemm<1><<<nb_mg, 256, 0, stream>>>(nullptr, nullptr, x, Wfm,
                                                  bc, dis, xwb, N);
        else
            k_mgemm<0><<<nb_mg, 256, 0, stream>>>(hh, hl, nullptr, Wfm,
                                                  nullptr, dis, xwb, N);
        if (layer == 2)
            k_agg<1><<<nb_agg, 256, 0, stream>>>(off4, csr, dis, xwb, b,
                                                 (float*)d_out, nullptr, nullptr, N);
        else
            k_agg<0><<<nb_agg, 256, 0, stream>>>(off4, csr, dis, xwb, b,
                                                 nullptr, hh, hl, N);
    }
}

// Round 19
// 156.227 us; speedup vs baseline: 5.0224x; 5.0224x over previous
//
#include <hip/hip_runtime.h>
#include <hip/hip_bf16.h>

// GCN encoder: h = relu(Agg(h @ W)) x3 (input linear folded into layer 0).
// N=20000 nodes, E=640000 edges, H=128.
// History: R2 CSR pull (3330->367) ... R7 MFMA bf16-split GEMM (245),
// R9/R10 bf16 payload + L2-sliced agg, de-LDS'd (197..193), R13 rank-trick
// CSR (169), R14 W_in@Ws0 fold (160), R15/R17 coop mega-kernel: grid.sync
// costs ~150us/sync on 8-XCD MI355X -> fusion dead (785us). R16 direct-x
// layer 0 (157.9us) is the base.
// R18: nt-store attempt -- compile error (builtin rejects HIP_vector_type).
// R19: same change via ext_vector_type aliases (f4x/u2x): agg outputs
//   written nontemporal so streaming hh/hl/out writes stop evicting the
//   L2-resident xwb slice (R9 FETCH=20.5MB vs 5MB unique = eviction
//   re-fetch). Warm-up phase dropped.
// ws: [dis N f][off4 4N+4 i][csr E i][rank E i][hh N*128 bf16][hl N*128 bf16]
//     [xwb 2xNx64 bf16][bc 128 f]      Wf = d_out[0:192KB] scratch.

#define HDIM 128

typedef __attribute__((ext_vector_type(8))) short s8v;
typedef __attribute__((ext_vector_type(4))) float f4v;
typedef __attribute__((ext_vector_type(4))) float f4x;   // nt-store friendly
typedef __attribute__((ext_vector_type(2))) uint u2x;    // nt-store friendly

__device__ __forceinline__ ushort f2bf(float f) {
    uint u = __float_as_uint(f);
    u += 0x7FFFu + ((u >> 16) & 1u);      // round-to-nearest-even
    return (ushort)(u >> 16);
}
__device__ __forceinline__ float bf2f(ushort h) {
    return __uint_as_float(((uint)h) << 16);
}
__device__ __forceinline__ void split8(float4 a, float4 b, s8v& hi, s8v& lo) {
    ushort h0 = f2bf(a.x), h1 = f2bf(a.y), h2 = f2bf(a.z), h3 = f2bf(a.w);
    ushort h4 = f2bf(b.x), h5 = f2bf(b.y), h6 = f2bf(b.z), h7 = f2bf(b.w);
    hi[0] = (short)h0; hi[1] = (short)h1; hi[2] = (short)h2; hi[3] = (short)h3;
    hi[4] = (short)h4; hi[5] = (short)h5; hi[6] = (short)h6; hi[7] = (short)h7;
    lo[0] = (short)f2bf(a.x - bf2f(h0)); lo[1] = (short)f2bf(a.y - bf2f(h1));
    lo[2] = (short)f2bf(a.z - bf2f(h2)); lo[3] = (short)f2bf(a.w - bf2f(h3));
    lo[4] = (short)f2bf(b.x - bf2f(h4)); lo[5] = (short)f2bf(b.y - bf2f(h5));
    lo[6] = (short)f2bf(b.z - bf2f(h6)); lo[7] = (short)f2bf(b.w - bf2f(h7));
}

// ---- CSR build: 4-way-split counters + rank trick --------------------------

__global__ __launch_bounds__(256) void k_count(const int* __restrict__ dst,
                                               int* __restrict__ off4,
                                               int* __restrict__ rank, int E4) {
    int t = blockIdx.x * 256 + threadIdx.x;
    if (t >= E4) return;
    int4 d = ((const int4*)dst)[t];
    int4 r;
    r.x = atomicAdd(&off4[d.x * 4 + 0], 1);
    r.y = atomicAdd(&off4[d.y * 4 + 1], 1);
    r.z = atomicAdd(&off4[d.z * 4 + 2], 1);
    r.w = atomicAdd(&off4[d.w * 4 + 3], 1);
    ((int4*)rank)[t] = r;
}

__global__ __launch_bounds__(256) void k_scan_blk(int* __restrict__ off4,
                                                  float* __restrict__ dis,
                                                  int* __restrict__ bsum, int N) {
    int t = threadIdx.x;
    int total = N * 4;
    int base = blockIdx.x * 1024 + t * 4;
    int4 d = make_int4(0, 0, 0, 0);
    if (base < total) {
        d = *(const int4*)(off4 + base);
        dis[base >> 2] = rsqrtf((float)(d.x + d.y + d.z + d.w + 1));
    }
    int tsum = d.x + d.y + d.z + d.w;
    int lane = t & 63;
    int incl = tsum;
    #pragma unroll
    for (int ofs = 1; ofs < 64; ofs <<= 1) {
        int u = __shfl_up(incl, ofs);
        if (lane >= ofs) incl += u;
    }
    __shared__ int wsum[4];
    if (lane == 63) wsum[t >> 6] = incl;
    __syncthreads();
    int w = t >> 6;
    int woff = 0;
    for (int i = 0; i < w; ++i) woff += wsum[i];

    int run = woff + incl - tsum;  // exclusive prefix (block-local)
    if (base < total) {
        off4[base + 0] = run; run += d.x;
        off4[base + 1] = run; run += d.y;
        off4[base + 2] = run; run += d.z;
        off4[base + 3] = run;
    }
    if (t == 255) bsum[blockIdx.x] = woff + incl;  // block total
}

__global__ __launch_bounds__(256) void k_scan_add(int* __restrict__ off4,
                                                  const int* __restrict__ bsum,
                                                  int N, int E) {
    int bid = blockIdx.x;
    if (bid == 0) {
        if (threadIdx.x == 0) off4[N * 4] = E;   // sentinel: end of last node
        return;
    }
    int p = 0;
    for (int i = 0; i < bid; ++i) p += bsum[i];
    int base = bid * 1024 + threadIdx.x * 4;
    if (base < N * 4) {
        int4 v = *(const int4*)(off4 + base);
        v.x += p; v.y += p; v.z += p; v.w += p;
        *(int4*)(off4 + base) = v;
    }
}

// atomic-free fill: csr[off4[dst*4+r] + rank] = src
__global__ __launch_bounds__(256) void k_fill(const int* __restrict__ src,
                                              const int* __restrict__ dst,
                                              const int* __restrict__ off4,
                                              const int* __restrict__ rank,
                                              int* __restrict__ csr, int E4) {
    int t = blockIdx.x * 256 + threadIdx.x;
    if (t >= E4) return;
    int4 s = ((const int4*)src)[t];
    int4 d = ((const int4*)dst)[t];
    int4 r = ((const int4*)rank)[t];
    csr[off4[d.x * 4 + 0] + r.x] = s.x;
    csr[off4[d.y * 4 + 1] + r.y] = s.y;
    csr[off4[d.z * 4 + 2] + r.z] = s.z;
    csr[off4[d.w * 4 + 3] + r.w] = s.w;
}

// ---- preprocessing ---------------------------------------------------------
// [0,nbZ): zero off4 | [nbZ,nbZ+192): wconv 3 matrices (m=0 computes
// Wc=W_in@Ws0 on the fly) | [nbZ+192]: bc = b_in@Ws0.
__global__ __launch_bounds__(256) void k_pre(const float* __restrict__ W_in,
                                             const float* __restrict__ Ws,
                                             const float* __restrict__ b_in,
                                             ushort* __restrict__ Wf,
                                             float* __restrict__ bc,
                                             int* __restrict__ off4,
                                             int N, int nbZ) {
    int bid = blockIdx.x;
    if (bid < nbZ) {
        int i = bid * 256 + threadIdx.x;
        if (i < N * 4 + 4) off4[i] = 0;
    } else if (bid < nbZ + 192) {
        int idx = (bid - nbZ) * 256 + threadIdx.x;   // 3 * 16384
        int m = idx >> 14;
        int e = idx & 16383;
        int k = e >> 7, col = e & 127;
        float w;
        if (m == 0) {
            // Wc[k][col] = sum_j W_in[k][j] * Ws0[j][col]
            w = 0.f;
            #pragma unroll 8
            for (int j = 0; j < 128; ++j)
                w = fmaf(W_in[k * 128 + j], Ws[j * 128 + col], w);
        } else {
            w = Ws[m * 16384 + k * 128 + col];
        }
        ushort hi = f2bf(w);
        ushort lo = f2bf(w - bf2f(hi));
        int ks = k >> 5, lk = (k >> 3) & 3, j = k & 7;
        int ct = col >> 4, lane = lk * 16 + (col & 15);
        int o = m * 32768 + (ks * 8 + ct) * 512 + lane * 8 + j;
        Wf[o] = hi;
        Wf[o + 16384] = lo;
    } else {
        int col = threadIdx.x;
        if (col < 128) {
            float v = 0.f;
            #pragma unroll 8
            for (int j = 0; j < 128; ++j)
                v = fmaf(b_in[j], Ws[j * 128 + col], v);
            bc[col] = v;
        }
    }
}

// ---- MFMA GEMM -------------------------------------------------------------
// xwb[slice][M][64] = bf16(((A) @ W + bias) * scale), 3-term bf16 split.
// L0=1: A from x (fp32), split to hi/lo in registers. L0=0: A from hh/hl.
// Col-half = bid&1 (block-level -> writer XCD parity == agg slice parity).
template<int L0>
__global__ __launch_bounds__(256) void k_mgemm(const ushort* Ahi, const ushort* Alo,
                                               const float* __restrict__ xf,
                                               const ushort* __restrict__ Wf,
                                               const float* __restrict__ bias,
                                               const float* __restrict__ scale,
                                               ushort* xwb, int M) {
    int l = threadIdx.x & 63;
    int ch = blockIdx.x & 1;
    int strip = (blockIdx.x >> 1) * 4 + (threadIdx.x >> 6);
    int r0 = strip * 16;
    int lr = l & 15, lk = l >> 4;
    int ar = r0 + lr; if (ar >= M) ar = M - 1;

    s8v ah0, ah1, ah2, ah3, al0, al1, al2, al3;
    if (L0) {
        const float* xr = xf + (long long)ar * HDIM + lk * 8;
        split8(*(const float4*)(xr),      *(const float4*)(xr + 4),  ah0, al0);
        split8(*(const float4*)(xr + 32), *(const float4*)(xr + 36), ah1, al1);
        split8(*(const float4*)(xr + 64), *(const float4*)(xr + 68), ah2, al2);
        split8(*(const float4*)(xr + 96), *(const float4*)(xr + 100), ah3, al3);
    } else {
        ah0 = *(const s8v*)(Ahi + (long long)ar * HDIM + lk * 8);
        ah1 = *(const s8v*)(Ahi + (long long)ar * HDIM + lk * 8 + 32);
        ah2 = *(const s8v*)(Ahi + (long long)ar * HDIM + lk * 8 + 64);
        ah3 = *(const s8v*)(Ahi + (long long)ar * HDIM + lk * 8 + 96);
        al0 = *(const s8v*)(Alo + (long long)ar * HDIM + lk * 8);
        al1 = *(const s8v*)(Alo + (long long)ar * HDIM + lk * 8 + 32);
        al2 = *(const s8v*)(Alo + (long long)ar * HDIM + lk * 8 + 64);
        al3 = *(const s8v*)(Alo + (long long)ar * HDIM + lk * 8 + 96);
    }

    f4v acc[4];
    #pragma unroll
    for (int c = 0; c < 4; ++c) acc[c] = (f4v){0.f, 0.f, 0.f, 0.f};

#define KSTEP(AH, AL, ksi)                                                          \
    {                                                                               \
        const ushort* wb = Wf + ((ksi) * 8 + ch * 4) * 512 + l * 8;                 \
        _Pragma("unroll")                                                           \
        for (int c = 0; c < 4; ++c) {                                               \
            s8v bh = *(const s8v*)(wb + c * 512);                                   \
            s8v bl = *(const s8v*)(wb + 16384 + c * 512);                           \
            acc[c] = __builtin_amdgcn_mfma_f32_16x16x32_bf16(AH, bh, acc[c], 0,0,0);\
            acc[c] = __builtin_amdgcn_mfma_f32_16x16x32_bf16(AH, bl, acc[c], 0,0,0);\
            acc[c] = __builtin_amdgcn_mfma_f32_16x16x32_bf16(AL, bh, acc[c], 0,0,0);\
        }                                                                           \
    }
    KSTEP(ah0, al0, 0)
    KSTEP(ah1, al1, 1)
    KSTEP(ah2, al2, 2)
    KSTEP(ah3, al3, 3)
#undef KSTEP

    if (r0 >= M) return;
    float bbv[4], sc[4];
    #pragma unroll
    for (int c = 0; c < 4; ++c) bbv[c] = bias ? bias[(ch * 4 + c) * 16 + lr] : 0.f;
    #pragma unroll
    for (int j = 0; j < 4; ++j) sc[j] = scale[r0 + lk * 4 + j];

    #pragma unroll
    for (int c = 0; c < 4; ++c) {
        #pragma unroll
        for (int j = 0; j < 4; ++j) {
            int row = r0 + lk * 4 + j;
            if (row >= M) continue;
            float o = (acc[c][j] + bbv[c]) * sc[j];
            int cc = c * 16 + lr;   // col within 64-col slice ch
            xwb[((long long)ch * M + row) * 64 + cc] = f2bf(o);
        }
    }
}

// ---- aggregation (L2-sliced, nt-store outputs) -----------------------------
// xwb [sl][row][64], 2.5MB/slice; slice = blockIdx&1 -> XCD parity.
// Quarter-wave edges (q=edge slot, t=col group), uint2 payload, 32-edge
// unroll, named int4 scalars, shfl_xor(16,32) reduce. Outputs written with
// nontemporal stores (ext_vector_type for builtin compatibility) so the
// streaming writes don't evict the hot slice from L2.
// LAST: fp32 d_out; else bf16 hi/lo split pair.
template<int LAST>
__global__ __launch_bounds__(256) void k_agg(const int* __restrict__ off4,
                                             const int* __restrict__ csr,
                                             const float* __restrict__ dis,
                                             const ushort* __restrict__ xwb,
                                             const float* __restrict__ b,
                                             float* __restrict__ outf,
                                             ushort* __restrict__ outhi,
                                             ushort* __restrict__ outlo, int N) {
    int lane = threadIdx.x & 63;
    int wv = threadIdx.x >> 6;
    int t = lane & 15, q = lane >> 4;
    int sl = blockIdx.x & 1;
    const ushort* xs = xwb + (long long)sl * N * 64;

    int v0 = (blockIdx.x >> 1) * 4 + wv;
    int vstride = (gridDim.x >> 1) * 4;

    float4 bb = ((const float4*)(b + sl * 64))[t];   // cols 4t..4t+3

#define GATH(sidx)                                                          \
    {                                                                       \
        uint2 u = *(const uint2*)(xs + (long long)(sidx) * 64 + (t << 2));  \
        ax += bf2f((ushort)u.x); ay += bf2f((ushort)(u.x >> 16));           \
        az += bf2f((ushort)u.y); aw += bf2f((ushort)(u.y >> 16));           \
    }
#define SEL(c) (q == 0 ? (c).x : q == 1 ? (c).y : q == 2 ? (c).z : (c).w)

    for (int v = v0; v < N; v += vstride) {
        int start = off4[v << 2];
        int end   = off4[(v << 2) + 4];
        float dv = dis[v];

        float ax = 0.f, ay = 0.f, az = 0.f, aw = 0.f;
        if (q == 0) GATH(v);                         // self term

        int i = start;
        for (; i + 32 <= end; i += 32) {
            int ib = __builtin_amdgcn_readfirstlane(i);
            int4 c0 = *(const int4*)(csr + ib);
            int4 c1 = *(const int4*)(csr + ib + 4);
            int4 c2 = *(const int4*)(csr + ib + 8);
            int4 c3 = *(const int4*)(csr + ib + 12);
            int4 c4 = *(const int4*)(csr + ib + 16);
            int4 c5 = *(const int4*)(csr + ib + 20);
            int4 c6 = *(const int4*)(csr + ib + 24);
            int4 c7 = *(const int4*)(csr + ib + 28);
            int s0 = SEL(c0), s1 = SEL(c1), s2 = SEL(c2), s3 = SEL(c3);
            int s4 = SEL(c4), s5 = SEL(c5), s6 = SEL(c6), s7 = SEL(c7);
            GATH(s0); GATH(s1); GATH(s2); GATH(s3);
            GATH(s4); GATH(s5); GATH(s6); GATH(s7);
        }
        if (i + 16 <= end) {
            int ib = __builtin_amdgcn_readfirstlane(i);
            int4 c0 = *(const int4*)(csr + ib);
            int4 c1 = *(const int4*)(csr + ib + 4);
            int4 c2 = *(const int4*)(csr + ib + 8);
            int4 c3 = *(const int4*)(csr + ib + 12);
            int s0 = SEL(c0), s1 = SEL(c1), s2 = SEL(c2), s3 = SEL(c3);
            GATH(s0); GATH(s1); GATH(s2); GATH(s3);
            i += 16;
        }
        if (i + 8 <= end) {
            int ib = __builtin_amdgcn_readfirstlane(i);
            int4 c0 = *(const int4*)(csr + ib);
            int4 c1 = *(const int4*)(csr + ib + 4);
            int s0 = SEL(c0), s1 = SEL(c1);
            GATH(s0); GATH(s1);
            i += 8;
        }
        if (i + 4 <= end) {
            int ib = __builtin_amdgcn_readfirstlane(i);
            int4 c0 = *(const int4*)(csr + ib);
            int s0 = SEL(c0);
            GATH(s0);
            i += 4;
        }
        {   // remainder 0..3 edges: one predicated round
            int r = end - i;
            if (q < r) {
                int s = csr[__builtin_amdgcn_readfirstlane(i) + q];
                GATH(s);
            }
        }

        ax += __shfl_xor(ax, 16); ax += __shfl_xor(ax, 32);
        ay += __shfl_xor(ay, 16); ay += __shfl_xor(ay, 32);
        az += __shfl_xor(az, 16); az += __shfl_xor(az, 32);
        aw += __shfl_xor(aw, 16); aw += __shfl_xor(aw, 32);

        if (q == 0) {
            float ox = fmaxf(fmaf(dv, ax, bb.x), 0.f);
            float oy = fmaxf(fmaf(dv, ay, bb.y), 0.f);
            float oz = fmaxf(fmaf(dv, az, bb.z), 0.f);
            float ow = fmaxf(fmaf(dv, aw, bb.w), 0.f);
            long long oidx = (long long)v * HDIM + sl * 64 + (t << 2);
            if (LAST) {
                f4x o4 = {ox, oy, oz, ow};
                __builtin_nontemporal_store(o4, (f4x*)(outf + oidx));
            } else {
                ushort h0 = f2bf(ox), h1 = f2bf(oy), h2 = f2bf(oz), h3 = f2bf(ow);
                u2x ph, pl;
                ph[0] = (uint)h0 | ((uint)h1 << 16);
                ph[1] = (uint)h2 | ((uint)h3 << 16);
                pl[0] = (uint)f2bf(ox - bf2f(h0)) | ((uint)f2bf(oy - bf2f(h1)) << 16);
                pl[1] = (uint)f2bf(oz - bf2f(h2)) | ((uint)f2bf(ow - bf2f(h3)) << 16);
                __builtin_nontemporal_store(ph, (u2x*)(outhi + oidx));
                __builtin_nontemporal_store(pl, (u2x*)(outlo + oidx));
            }
        }
    }
#undef GATH
#undef SEL
}

extern "C" void kernel_launch(void* const* d_in, const int* in_sizes, int n_in,
                              void* d_out, int out_size, void* d_ws, size_t ws_size,
                              hipStream_t stream) {
    const float* x    = (const float*)d_in[0];
    const int*   ei   = (const int*)d_in[1];   // [2, E]: first E = src, next E = dst
    const float* W_in = (const float*)d_in[2];
    const float* b_in = (const float*)d_in[3];
    const float* Ws   = (const float*)d_in[4]; // [3,128,128]
    const float* bs   = (const float*)d_in[5]; // [3,128]

    const int N = in_sizes[0] / HDIM;
    const int E = in_sizes[1] / 2;
    const int* src = ei;
    const int* dst = ei + E;

    float*  dis  = (float*)d_ws;                     // N floats
    int*    off4 = (int*)(dis + N);                  // 4N+4 ints (excl prefix)
    int*    csr  = off4 + 4 * N + 4;                 // E ints (first ~80 = scan bsums, transient)
    int*    rank = csr + E;                          // E ints
    ushort* hh   = (ushort*)(rank + E);              // N*128 bf16 (h hi, row-major)
    ushort* hl   = hh + (long long)N * HDIM;         // N*128 bf16 (h lo, row-major)
    ushort* xwb  = hl + (long long)N * HDIM;         // [2][N][64] bf16, dis-prescaled
    float*  bc   = (float*)(xwb + (long long)2 * N * 64); // 128 floats (b_in@Ws0)
    ushort* Wf   = (ushort*)d_out;                   // 3*64KB scratch, overwritten by last agg

    int nbZ     = (4 * N + 4 + 255) / 256;
    int nb_E4   = (E / 4 + 255) / 256;
    int nb_scan = (4 * N + 1023) / 1024;
    int strips  = (N + 15) / 16;
    int nb_mg   = 2 * ((strips + 3) / 4);
    int nb_pre  = nbZ + 192 + 1;
    int nb_agg  = 2048;

    // preprocessing: zero off4 | Wc/W1/W2 fragments | bc
    k_pre<<<nb_pre, 256, 0, stream>>>(W_in, Ws, b_in, Wf, bc, off4, N, nbZ);

    // CSR build + dis: count(+rank) -> scan -> atomic-free fill
    k_count   <<<nb_E4,   256, 0, stream>>>(dst, off4, rank, E / 4);
    k_scan_blk<<<nb_scan, 256, 0, stream>>>(off4, dis, csr, N);
    k_scan_add<<<nb_scan, 256, 0, stream>>>(off4, csr, N, E);
    k_fill    <<<nb_E4,   256, 0, stream>>>(src, dst, off4, rank, csr, E / 4);

    for (int layer = 0; layer < 3; ++layer) {
        const ushort* Wfm = Wf + (long long)layer * 32768;
        const float* b = bs + (long long)layer * HDIM;
        if (layer == 0)
            k_mgemm<1><<<nb_mg, 256, 0, stream>>>(nullptr, nullptr, x, Wfm,
                                                  bc, dis, xwb, N);
        else
            k_mgemm<0><<<nb_mg, 256, 0, stream>>>(hh, hl, nullptr, Wfm,
                                                  nullptr, dis, xwb, N);
        if (layer == 2)
            k_agg<1><<<nb_agg, 256, 0, stream>>>(off4, csr, dis, xwb, b,
                                                 (float*)d_out, nullptr, nullptr, N);
        else
            k_agg<0><<<nb_agg, 256, 0, stream>>>(off4, csr, dis, xwb, b,
                                                 nullptr, hh, hl, N);
    }
}